// Round 3
// baseline (148.310 us; speedup 1.0000x reference)
//
#include <hip/hip_runtime.h>
#include <hip/hip_bf16.h>
#include <math.h>

// Problem constants
#define BB 4
#define CC 64
#define HH 128
#define WW 128
#define HW 16384
#define CHW (CC*HW)

typedef __bf16 bf16;
typedef __attribute__((ext_vector_type(8))) __bf16 bf16x8;
typedef __attribute__((ext_vector_type(4))) __bf16 bf16x4;
typedef __attribute__((ext_vector_type(4))) float f32x4;
typedef __attribute__((ext_vector_type(4))) unsigned short u16x4;

#define MFMA(a, b, c) __builtin_amdgcn_mfma_f32_16x16x32_bf16((a), (b), (c), 0, 0, 0)

// ---- Pre-kernel: x NCHW -> NHWC bf16 (blocks 0..1023) + weight frags ----
__global__ __launch_bounds__(256) void k_pre(const float* __restrict__ x,
        bf16* __restrict__ xt,
        const float* __restrict__ dw, const float* __restrict__ ow,
        const float* __restrict__ mw,
        bf16* __restrict__ wfd_hi, bf16* __restrict__ wfd_lo,
        bf16* __restrict__ wfo_hi, bf16* __restrict__ wfo_lo) {
    __shared__ float tile[64][65];
    if (blockIdx.x < 1024) {
        int b    = blockIdx.x >> 8;
        int s0   = (blockIdx.x & 255) * 64;
        int lane = threadIdx.x & 63;
        int w    = threadIdx.x >> 6;
        const float* xb = x + (size_t)b * CHW;
        #pragma unroll
        for (int r = 0; r < 16; ++r) {
            int c = w * 16 + r;
            tile[c][lane] = xb[(size_t)c * HW + s0 + lane];
        }
        __syncthreads();
        bf16* xtb = xt + (size_t)b * CHW;
        #pragma unroll
        for (int it = 0; it < 2; ++it) {
            int task = it * 256 + threadIdx.x;      // 512 tasks: 64 s x 8 ch-chunks
            int s = task >> 3, ch0 = (task & 7) * 8;
            bf16x8 v;
            #pragma unroll
            for (int j = 0; j < 8; ++j) v[j] = (bf16)tile[ch0 + j][s];
            *(bf16x8*)&xtb[(size_t)(s0 + s) * 64 + ch0] = v;
        }
    } else {
        int idx = (blockIdx.x - 1024) * 256 + threadIdx.x;
        if (idx < 36864) {                          // deform frags: 4 nt * 18 ks * 64 lanes * 8
            int j    = idx & 7;
            int lane = (idx >> 3) & 63;
            int ks   = (idx >> 9) % 18;
            int nt   = idx / (512 * 18);
            int n    = nt * 16 + (lane & 15);
            int kglob = ks * 32 + (lane >> 4) * 8 + j;
            int kk = kglob >> 6, c = kglob & 63;    // K-order: k = kk*64 + c
            float w = dw[(n * 64 + c) * 9 + kk];
            bf16 h = (bf16)w;
            wfd_hi[idx] = h;
            wfd_lo[idx] = (bf16)(w - (float)h);
        } else {
            int idx2 = idx - 36864;                 // offmask frags: 2 nt
            int j    = idx2 & 7;
            int lane = (idx2 >> 3) & 63;
            int ks   = (idx2 >> 9) % 18;
            int nt   = idx2 / (512 * 18);
            int ch   = nt * 16 + (lane & 15);
            int kglob = ks * 32 + (lane >> 4) * 8 + j;
            int kk = kglob >> 6, c = kglob & 63;
            float w = 0.0f;
            if (ch < 18)      w = ow[(ch * 64 + c) * 9 + kk];
            else if (ch < 27) w = mw[((ch - 18) * 64 + c) * 9 + kk];
            bf16 h = (bf16)w;
            wfo_hi[idx2] = h;
            wfo_lo[idx2] = (bf16)(w - (float)h);
        }
    }
}

// ---- Fused kernel, wave-PAIR per st, kk-split halves every serial chain ----
// 8 waves/block (512 thr). Pair p owns st=p. Within a pair, half=0/1 each:
//   B : offset/mask GEMM over its kk-half -> partial om in scratch; barrier;
//       both waves combine partials (+bias,+sigmoid) -> shared om_s; barrier.
//   C1: 144 bilinear scalar tasks, redundantly per wave -> shared samp.
//   D : deform GEMM over its kk-half (gather->A-frags in registers);
//       half=1 writes partial acc to scratch; barrier; half=0 adds+stores.
// Forced 64-VGPR budget (launch_bounds 512,8) -> 32 waves/CU occupancy.
__global__ __launch_bounds__(512, 8) void k_fused(const bf16* __restrict__ xt,
        const bf16* __restrict__ wfo_hi, const bf16* __restrict__ wfo_lo,
        const bf16* __restrict__ wfd_hi,
        const float* __restrict__ ob, const float* __restrict__ mb,
        const float* __restrict__ db, float* __restrict__ out) {
    // scratch: per-pair 4096 B region. Early life: B partial om (half*1728).
    // Late life: D partial acc (nt-major: nt*1024 + lane*16). Lifetimes
    // separated by the barrier after the om-combine step.
    __shared__ __align__(16) char scratch_s[4 * 4096];          // 16384 B
    __shared__ __align__(16) float om_s[4 * 27 * 16];           // 6912 B
    __shared__ __align__(8)  bf16 sampw[4 * 144 * 4];           // 4608 B
    __shared__ __align__(8)  unsigned short sampo[4 * 144 * 4]; // 4608 B

    // XCD-chunked swizzle (1024 blocks, 8 XCDs, bijective)
    int bid = (blockIdx.x & 7) * 128 + (blockIdx.x >> 3);
    int pos0 = bid * 64;
    int wo0 = pos0 & 127;
    int ho  = (pos0 >> 7) & 127;
    int b   = pos0 >> 14;
    int t = threadIdx.x, wave = t >> 6, lane = t & 63;
    int pair = wave >> 1, half = wave & 1;
    int st = pair;
    int m = lane & 15, g = lane >> 4;
    const bf16* xtb = xt + (size_t)b * CHW;

    // ---- Phase B: offset/mask GEMM, this wave's kk-half ----
    f32x4 acc0 = {0.f, 0.f, 0.f, 0.f};
    f32x4 acc1 = {0.f, 0.f, 0.f, 0.f};
    {
        const bf16x8* bh0 = (const bf16x8*)wfo_hi + lane;
        const bf16x8* bl0 = (const bf16x8*)wfo_lo + lane;
        const bf16x8* bh1 = (const bf16x8*)wfo_hi + 18 * 64 + lane;
        const bf16x8* bl1 = (const bf16x8*)wfo_lo + 18 * 64 + lane;
        int nB  = half ? 4 : 5;
        int kkB = half ? 5 : 0;
        for (int i = 0; i < nB; ++i) {
            int kk = kkB + i;
            int y  = ho + kk / 3 - 1;
            int xx = wo0 + st * 16 + m + (kk % 3) - 1;
            bf16x8 ae = {};
            bf16x8 ao = {};
            if ((unsigned)y < 128u && (unsigned)xx < 128u) {
                const bf16* bp = xtb + ((size_t)(y * 128 + xx) << 6);
                ae = *(const bf16x8*)(bp + g * 8);
                ao = *(const bf16x8*)(bp + 32 + g * 8);
            }
            int ks0 = 2 * kk, ks1 = 2 * kk + 1;
            acc0 = MFMA(ae, bh0[ks0 * 64], acc0);
            acc0 = MFMA(ae, bl0[ks0 * 64], acc0);
            acc0 = MFMA(ao, bh0[ks1 * 64], acc0);
            acc0 = MFMA(ao, bl0[ks1 * 64], acc0);
            acc1 = MFMA(ae, bh1[ks0 * 64], acc1);
            acc1 = MFMA(ae, bl1[ks0 * 64], acc1);
            acc1 = MFMA(ao, bh1[ks1 * 64], acc1);
            acc1 = MFMA(ao, bl1[ks1 * 64], acc1);
        }
    }
    // write partial om: lane (m,g) reg r -> om[ch][p_local], ch=m / 16+m, p=g*4+r
    int ch1 = 16 + m;
    {
        float* op = (float*)(scratch_s + pair * 4096 + half * 1728);
        *(f32x4*)&op[m * 16 + g * 4] = acc0;
        if (ch1 < 27) *(f32x4*)&op[ch1 * 16 + g * 4] = acc1;
    }
    __syncthreads();

    // combine partials + bias + sigmoid -> om_s (both waves, identical values)
    float* omw = om_s + pair * 27 * 16;
    {
        const float* pp = (const float*)(scratch_s + pair * 4096 + (half ^ 1) * 1728);
        f32x4 p0 = *(const f32x4*)&pp[m * 16 + g * 4];
        float bias0 = ob[m];
        f32x4 v0;
        #pragma unroll
        for (int r = 0; r < 4; ++r) v0[r] = acc0[r] + p0[r] + bias0;
        *(f32x4*)&omw[m * 16 + g * 4] = v0;
        if (ch1 < 27) {
            f32x4 p1 = *(const f32x4*)&pp[ch1 * 16 + g * 4];
            float bias1 = (ch1 < 18) ? ob[ch1] : mb[ch1 - 18];
            f32x4 v1;
            #pragma unroll
            for (int r = 0; r < 4; ++r) {
                float v = acc1[r] + p1[r] + bias1;
                if (ch1 >= 18) v = 1.0f / (1.0f + __expf(-v));
                v1[r] = v;
            }
            *(f32x4*)&omw[ch1 * 16 + g * 4] = v1;
        }
    }
    __syncthreads();    // om_s visible; also ends scratch's om-partial lifetime

    // ---- Phase C1: 144 bilinear scalar tasks (redundant per wave) ----
    bf16* swv = sampw + pair * 144 * 4;
    unsigned short* sov = sampo + pair * 144 * 4;
    #pragma unroll
    for (int i = 0; i < 3; ++i) {
        int task = i * 64 + lane;
        if (task < 144) {
            int p = task / 9, k = task - p * 9;
            float dy = omw[(2 * k) * 16 + p];
            float dx = omw[(2 * k + 1) * 16 + p];
            float mk = omw[(18 + k) * 16 + p];
            float py = (float)(ho - 1 + k / 3) + dy;
            float px = (float)(wo0 + st * 16 + p - 1 + (k % 3)) + dx;
            float y0f = floorf(py), x0f = floorf(px);
            float fy = py - y0f, fx = px - x0f;
            int y0 = (int)y0f, x0 = (int)x0f;
            int y1 = y0 + 1,  x1 = x0 + 1;
            bool vy0 = (unsigned)y0 < 128u, vy1 = (unsigned)y1 < 128u;
            bool vx0 = (unsigned)x0 < 128u, vx1 = (unsigned)x1 < 128u;
            int y0c = min(max(y0, 0), 127), y1c = min(max(y1, 0), 127);
            int x0c = min(max(x0, 0), 127), x1c = min(max(x1, 0), 127);
            bf16x4 wv;
            wv.x = (bf16)((vy0 && vx0) ? mk * (1.f - fy) * (1.f - fx) : 0.f);
            wv.y = (bf16)((vy0 && vx1) ? mk * (1.f - fy) * fx         : 0.f);
            wv.z = (bf16)((vy1 && vx0) ? mk * fy * (1.f - fx)         : 0.f);
            wv.w = (bf16)((vy1 && vx1) ? mk * fy * fx                 : 0.f);
            u16x4 ov;
            ov.x = (unsigned short)(y0c * 128 + x0c);
            ov.y = (unsigned short)(y0c * 128 + x1c);
            ov.z = (unsigned short)(y1c * 128 + x0c);
            ov.w = (unsigned short)(y1c * 128 + x1c);
            *(bf16x4*)&swv[task * 4] = wv;
            *(u16x4*)&sov[task * 4] = ov;
        }
    }
    asm volatile("s_waitcnt lgkmcnt(0)" ::: "memory");  // own writes cover all tasks

    // ---- Phase D: gather into A-frags + deform GEMM, this wave's kk-half ----
    const bf16x8* bfd = (const bf16x8*)wfd_hi + lane;
    f32x4 acc[4];
    #pragma unroll
    for (int nt = 0; nt < 4; ++nt) acc[nt] = (f32x4){0.f, 0.f, 0.f, 0.f};
    int sb = m * 9 * 4;
    int nD  = half ? 5 : 4;     // balance: B 5+4, D 4+5
    int kkD = half ? 0 : 5;
    for (int i = 0; i < nD; ++i) {
        int kk = kkD + i;
        bf16x4 wb = *(const bf16x4*)&swv[sb + kk * 4];
        u16x4  o4 = *(const u16x4*)&sov[sb + kk * 4];
        const bf16* p00 = xtb + (((int)o4.x) << 6) + g * 8;
        const bf16* p01 = xtb + (((int)o4.y) << 6) + g * 8;
        const bf16* p10 = xtb + (((int)o4.z) << 6) + g * 8;
        const bf16* p11 = xtb + (((int)o4.w) << 6) + g * 8;
        float w00 = (float)wb.x, w01 = (float)wb.y;
        float w10 = (float)wb.z, w11 = (float)wb.w;
        float f0[8], f1[8];
        bf16x8 v;
        v = *(const bf16x8*)p00;
        #pragma unroll
        for (int j = 0; j < 8; ++j) f0[j] = w00 * (float)v[j];
        v = *(const bf16x8*)(p00 + 32);
        #pragma unroll
        for (int j = 0; j < 8; ++j) f1[j] = w00 * (float)v[j];
        v = *(const bf16x8*)p01;
        #pragma unroll
        for (int j = 0; j < 8; ++j) f0[j] += w01 * (float)v[j];
        v = *(const bf16x8*)(p01 + 32);
        #pragma unroll
        for (int j = 0; j < 8; ++j) f1[j] += w01 * (float)v[j];
        v = *(const bf16x8*)p10;
        #pragma unroll
        for (int j = 0; j < 8; ++j) f0[j] += w10 * (float)v[j];
        v = *(const bf16x8*)(p10 + 32);
        #pragma unroll
        for (int j = 0; j < 8; ++j) f1[j] += w10 * (float)v[j];
        v = *(const bf16x8*)p11;
        #pragma unroll
        for (int j = 0; j < 8; ++j) f0[j] += w11 * (float)v[j];
        v = *(const bf16x8*)(p11 + 32);
        #pragma unroll
        for (int j = 0; j < 8; ++j) f1[j] += w11 * (float)v[j];
        bf16x8 af0, af1;
        #pragma unroll
        for (int j = 0; j < 8; ++j) { af0[j] = (bf16)f0[j]; af1[j] = (bf16)f1[j]; }
        int ks0 = 2 * kk, ks1 = 2 * kk + 1;
        acc[0] = MFMA(af0, bfd[(0 * 18 + ks0) * 64], acc[0]);
        acc[0] = MFMA(af1, bfd[(0 * 18 + ks1) * 64], acc[0]);
        acc[1] = MFMA(af0, bfd[(1 * 18 + ks0) * 64], acc[1]);
        acc[1] = MFMA(af1, bfd[(1 * 18 + ks1) * 64], acc[1]);
        acc[2] = MFMA(af0, bfd[(2 * 18 + ks0) * 64], acc[2]);
        acc[2] = MFMA(af1, bfd[(2 * 18 + ks1) * 64], acc[2]);
        acc[3] = MFMA(af0, bfd[(3 * 18 + ks0) * 64], acc[3]);
        acc[3] = MFMA(af1, bfd[(3 * 18 + ks1) * 64], acc[3]);
    }

    // ---- pair reduce + store (half=0 stores) ----
    float* dre = (float*)(scratch_s + pair * 4096);     // nt-major: uniform banks
    if (half) {
        #pragma unroll
        for (int nt = 0; nt < 4; ++nt)
            *(f32x4*)&dre[nt * 256 + lane * 4] = acc[nt];
    }
    __syncthreads();
    if (!half) {
        #pragma unroll
        for (int nt = 0; nt < 4; ++nt) {
            f32x4 pa = *(const f32x4*)&dre[nt * 256 + lane * 4];
            int o = nt * 16 + m;
            float bias = db[o];
            float4 vv = {acc[nt][0] + pa[0] + bias, acc[nt][1] + pa[1] + bias,
                         acc[nt][2] + pa[2] + bias, acc[nt][3] + pa[3] + bias};
            *(float4*)&out[((size_t)(b * 64 + o)) * HW + ho * 128 + wo0 + st * 16 + g * 4] = vv;
        }
    }
}

extern "C" void kernel_launch(void* const* d_in, const int* in_sizes, int n_in,
                              void* d_out, int out_size, void* d_ws, size_t ws_size,
                              hipStream_t stream) {
    const float* x   = (const float*)d_in[0];
    const float* ow  = (const float*)d_in[1];
    const float* ob  = (const float*)d_in[2];
    const float* mw  = (const float*)d_in[3];
    const float* mb  = (const float*)d_in[4];
    const float* dw  = (const float*)d_in[5];
    const float* db  = (const float*)d_in[6];
    float* out = (float*)d_out;

    bf16* xt = (bf16*)d_ws;                         // 4,194,304 bf16 = 8 MB
    bf16* wfd_hi = xt + (size_t)BB * HW * CC;
    bf16* wfd_lo = wfd_hi + 36864;
    bf16* wfo_hi = wfd_lo + 36864;
    bf16* wfo_lo = wfo_hi + 18432;

    k_pre<<<1024 + 216, 256, 0, stream>>>(x, xt, dw, ow, mw, wfd_hi, wfd_lo, wfo_hi, wfo_lo);
    k_fused<<<(BB * HW) / 64, 512, 0, stream>>>(xt, wfo_hi, wfo_lo, wfd_hi, ob, mb, db, out);
}

// Round 4
// 121.731 us; speedup vs baseline: 1.2183x; 1.2183x over previous
//
#include <hip/hip_runtime.h>
#include <hip/hip_bf16.h>
#include <math.h>

// Problem constants
#define BB 4
#define CC 64
#define HH 128
#define WW 128
#define HW 16384
#define CHW (CC*HW)

typedef __bf16 bf16;
typedef __attribute__((ext_vector_type(8))) __bf16 bf16x8;
typedef __attribute__((ext_vector_type(4))) __bf16 bf16x4;
typedef __attribute__((ext_vector_type(4))) float f32x4;
typedef __attribute__((ext_vector_type(4))) unsigned short u16x4;

#define MFMA(a, b, c) __builtin_amdgcn_mfma_f32_16x16x32_bf16((a), (b), (c), 0, 0, 0)

// ---- Pre-kernel: x NCHW -> NHWC bf16 (blocks 0..1023) + weight frags ----
__global__ __launch_bounds__(256) void k_pre(const float* __restrict__ x,
        bf16* __restrict__ xt,
        const float* __restrict__ dw, const float* __restrict__ ow,
        const float* __restrict__ mw,
        bf16* __restrict__ wfd_hi, bf16* __restrict__ wfd_lo,
        bf16* __restrict__ wfo_hi, bf16* __restrict__ wfo_lo) {
    __shared__ float tile[64][65];
    if (blockIdx.x < 1024) {
        int b    = blockIdx.x >> 8;
        int s0   = (blockIdx.x & 255) * 64;
        int lane = threadIdx.x & 63;
        int w    = threadIdx.x >> 6;
        const float* xb = x + (size_t)b * CHW;
        #pragma unroll
        for (int r = 0; r < 16; ++r) {
            int c = w * 16 + r;
            tile[c][lane] = xb[(size_t)c * HW + s0 + lane];
        }
        __syncthreads();
        bf16* xtb = xt + (size_t)b * CHW;
        #pragma unroll
        for (int it = 0; it < 2; ++it) {
            int task = it * 256 + threadIdx.x;      // 512 tasks: 64 s x 8 ch-chunks
            int s = task >> 3, ch0 = (task & 7) * 8;
            bf16x8 v;
            #pragma unroll
            for (int j = 0; j < 8; ++j) v[j] = (bf16)tile[ch0 + j][s];
            *(bf16x8*)&xtb[(size_t)(s0 + s) * 64 + ch0] = v;
        }
    } else {
        int idx = (blockIdx.x - 1024) * 256 + threadIdx.x;
        if (idx < 36864) {                          // deform frags: 4 nt * 18 ks * 64 lanes * 8
            int j    = idx & 7;
            int lane = (idx >> 3) & 63;
            int ks   = (idx >> 9) % 18;
            int nt   = idx / (512 * 18);
            int n    = nt * 16 + (lane & 15);
            int kglob = ks * 32 + (lane >> 4) * 8 + j;
            int kk = kglob >> 6, c = kglob & 63;    // K-order: k = kk*64 + c
            float w = dw[(n * 64 + c) * 9 + kk];
            bf16 h = (bf16)w;
            wfd_hi[idx] = h;
            wfd_lo[idx] = (bf16)(w - (float)h);
        } else {
            int idx2 = idx - 36864;                 // offmask frags: 2 nt
            int j    = idx2 & 7;
            int lane = (idx2 >> 3) & 63;
            int ks   = (idx2 >> 9) % 18;
            int nt   = idx2 / (512 * 18);
            int ch   = nt * 16 + (lane & 15);
            int kglob = ks * 32 + (lane >> 4) * 8 + j;
            int kk = kglob >> 6, c = kglob & 63;
            float w = 0.0f;
            if (ch < 18)      w = ow[(ch * 64 + c) * 9 + kk];
            else if (ch < 27) w = mw[((ch - 18) * 64 + c) * 9 + kk];
            bf16 h = (bf16)w;
            wfo_hi[idx2] = h;
            wfo_lo[idx2] = (bf16)(w - (float)h);
        }
    }
}

// ---- Fused kernel: R0 pipeline + XCD swizzle + 16B paired-st gather ----
// B : offset/mask GEMM, wave = st, A-frags direct from global -> om_s
// C1: 576 tasks precompute bilinear scalars -> sampw/sampo
// per st-PAIR sp (2 sts at once, 16B gather loads):
//   C2: thread (half,prow,c8) gathers 8 channels of row prow, st=2sp+half,
//       all 9 kk -> a_s2[half] in the swizzled MFMA-A-frag layout
//   D : deform GEMM for st=2sp and 2sp+1 (wave = o-tile), hi-only
__global__ __launch_bounds__(256) void k_fused(const bf16* __restrict__ xt,
        const bf16* __restrict__ wfo_hi, const bf16* __restrict__ wfo_lo,
        const bf16* __restrict__ wfd_hi,
        const float* __restrict__ ob, const float* __restrict__ mb,
        const float* __restrict__ db, float* __restrict__ out) {
    __shared__ __align__(16) bf16 a_s2[2][18 * 64 * 8];    // 36864 B (st-pair)
    __shared__ float om_s[27 * 64];                        // 6912 B
    __shared__ __align__(8) bf16 sampw[576 * 4];           // 4608 B
    __shared__ __align__(8) unsigned short sampo[576 * 4]; // 4608 B

    // XCD-chunked swizzle (1024 blocks, 8 XCDs, bijective)
    int bid = (blockIdx.x & 7) * 128 + (blockIdx.x >> 3);
    int pos0 = bid * 64;
    int wo0 = pos0 & 127;
    int ho  = (pos0 >> 7) & 127;
    int b   = pos0 >> 14;
    int t = threadIdx.x, wave = t >> 6, lane = t & 63;
    int m = lane & 15, g = lane >> 4;
    const bf16* xtb = xt + (size_t)b * CHW;

    // ---- Phase B: offset/mask GEMM, wave = st, A-frags direct from global ----
    {
        int st = wave;
        f32x4 acc0 = {0.f, 0.f, 0.f, 0.f};
        f32x4 acc1 = {0.f, 0.f, 0.f, 0.f};
        const bf16x8* bh0 = (const bf16x8*)wfo_hi + lane;
        const bf16x8* bl0 = (const bf16x8*)wfo_lo + lane;
        const bf16x8* bh1 = (const bf16x8*)wfo_hi + 18 * 64 + lane;
        const bf16x8* bl1 = (const bf16x8*)wfo_lo + 18 * 64 + lane;
        #pragma unroll
        for (int kk = 0; kk < 9; ++kk) {
            int y  = ho + kk / 3 - 1;
            int xx = wo0 + st * 16 + m + (kk % 3) - 1;
            bf16x8 ae = {};
            bf16x8 ao = {};
            if ((unsigned)y < 128u && (unsigned)xx < 128u) {
                const bf16* bp = xtb + ((size_t)(y * 128 + xx) << 6);
                ae = *(const bf16x8*)(bp + g * 8);
                ao = *(const bf16x8*)(bp + 32 + g * 8);
            }
            int ks0 = 2 * kk, ks1 = 2 * kk + 1;
            acc0 = MFMA(ae, bh0[ks0 * 64], acc0);
            acc0 = MFMA(ae, bl0[ks0 * 64], acc0);
            acc0 = MFMA(ao, bh0[ks1 * 64], acc0);
            acc0 = MFMA(ao, bl0[ks1 * 64], acc0);
            acc1 = MFMA(ae, bh1[ks0 * 64], acc1);
            acc1 = MFMA(ae, bl1[ks0 * 64], acc1);
            acc1 = MFMA(ao, bh1[ks1 * 64], acc1);
            acc1 = MFMA(ao, bl1[ks1 * 64], acc1);
        }
        int p64 = st * 16 + g * 4;
        float bias0 = ob[m];                        // ch = m, always < 18
        #pragma unroll
        for (int r = 0; r < 4; ++r)
            om_s[m * 64 + p64 + r] = acc0[r] + bias0;
        int ch1 = 16 + m;
        if (ch1 < 27) {
            float bias1 = (ch1 < 18) ? ob[ch1] : mb[ch1 - 18];
            #pragma unroll
            for (int r = 0; r < 4; ++r) {
                float v = acc1[r] + bias1;
                if (ch1 >= 18) v = 1.0f / (1.0f + __expf(-v));
                om_s[ch1 * 64 + p64 + r] = v;
            }
        }
    }
    __syncthreads();

    // ---- Phase C1: bilinear scalar precompute (576 tasks) ----
    for (int task = t; task < 576; task += 256) {
        int p64 = task / 9, k = task - p64 * 9;
        float dy = om_s[(2 * k) * 64 + p64];
        float dx = om_s[(2 * k + 1) * 64 + p64];
        float mk = om_s[(18 + k) * 64 + p64];
        float py = (float)(ho - 1 + k / 3) + dy;
        float px = (float)(wo0 + p64 - 1 + (k % 3)) + dx;
        float y0f = floorf(py), x0f = floorf(px);
        float fy = py - y0f, fx = px - x0f;
        int y0 = (int)y0f, x0 = (int)x0f;
        int y1 = y0 + 1,  x1 = x0 + 1;
        bool vy0 = (unsigned)y0 < 128u, vy1 = (unsigned)y1 < 128u;
        bool vx0 = (unsigned)x0 < 128u, vx1 = (unsigned)x1 < 128u;
        int y0c = min(max(y0, 0), 127), y1c = min(max(y1, 0), 127);
        int x0c = min(max(x0, 0), 127), x1c = min(max(x1, 0), 127);
        bf16x4 wv;
        wv.x = (bf16)((vy0 && vx0) ? mk * (1.f - fy) * (1.f - fx) : 0.f);
        wv.y = (bf16)((vy0 && vx1) ? mk * (1.f - fy) * fx         : 0.f);
        wv.z = (bf16)((vy1 && vx0) ? mk * fy * (1.f - fx)         : 0.f);
        wv.w = (bf16)((vy1 && vx1) ? mk * fy * fx                 : 0.f);
        u16x4 ov;
        ov.x = (unsigned short)(y0c * 128 + x0c);
        ov.y = (unsigned short)(y0c * 128 + x1c);
        ov.z = (unsigned short)(y1c * 128 + x0c);
        ov.w = (unsigned short)(y1c * 128 + x1c);
        *(bf16x4*)&sampw[task * 4] = wv;
        *(u16x4*)&sampo[task * 4] = ov;
    }
    __syncthreads();

    // ---- st-pair loop: C2 (16B gather, 2 sts) -> D GEMM x2 ----
    const bf16x8* bhd = (const bf16x8*)wfd_hi + (size_t)wave * 18 * 64 + lane;
    int fle = ((m ^ g) + (g << 4)) * 8;             // D-read offsets (elements)
    int flo = ((m ^ g ^ 4) + (g << 4)) * 8;
    // C2 thread mapping: half selects st within pair; prow = row in st;
    // c8 = 8-channel chunk. ks parity = kpar is loop-invariant.
    int half = t >> 7;
    int prow = (t >> 3) & 15;
    int c8   = (t & 7) * 8;
    int kpar = c8 >> 5;
    int gch  = (c8 & 31) >> 3;
    int flw  = (prow ^ gch ^ (kpar << 2)) + (gch << 4);   // write slot (16B units)
    char* abw = (char*)&a_s2[half][0] + (flw << 4);

    #pragma unroll
    for (int sp = 0; sp < 2; ++sp) {
        // C2: gather rows of sts {2sp, 2sp+1} into a_s2[0]/a_s2[1]
        int stc = sp * 2 + half;
        int taskbase = (stc * 16 + prow) * 9;
        #pragma unroll
        for (int kk = 0; kk < 9; ++kk) {
            int task = taskbase + kk;
            bf16x4 wb = *(const bf16x4*)&sampw[task * 4];
            u16x4  o4 = *(const u16x4*)&sampo[task * 4];
            bf16x8 v00 = *(const bf16x8*)&xtb[((int)o4.x << 6) + c8];
            bf16x8 v01 = *(const bf16x8*)&xtb[((int)o4.y << 6) + c8];
            bf16x8 v10 = *(const bf16x8*)&xtb[((int)o4.z << 6) + c8];
            bf16x8 v11 = *(const bf16x8*)&xtb[((int)o4.w << 6) + c8];
            float w00 = (float)wb.x, w01 = (float)wb.y;
            float w10 = (float)wb.z, w11 = (float)wb.w;
            bf16x8 hv;
            #pragma unroll
            for (int j = 0; j < 8; ++j) {
                float r = w00 * (float)v00[j] + w01 * (float)v01[j]
                        + w10 * (float)v10[j] + w11 * (float)v11[j];
                hv[j] = (bf16)r;
            }
            int ks = 2 * kk + kpar;
            *(bf16x8*)(abw + (ks << 10)) = hv;      // byte (ks*64+flw)<<4
        }
        __syncthreads();

        // D: deform GEMM for the two sts of this pair, wave = o-tile
        #pragma unroll
        for (int h2 = 0; h2 < 2; ++h2) {
            int st = sp * 2 + h2;
            const bf16* ab = &a_s2[h2][0];
            f32x4 acc = {0.f, 0.f, 0.f, 0.f};
            __builtin_amdgcn_s_setprio(1);
            #pragma unroll
            for (int kk = 0; kk < 9; ++kk) {
                bf16x8 a0 = *(const bf16x8*)&ab[(2 * kk) * 512 + fle];
                bf16x8 a1 = *(const bf16x8*)&ab[(2 * kk + 1) * 512 + flo];
                acc = MFMA(a0, bhd[(2 * kk) * 64], acc);
                acc = MFMA(a1, bhd[(2 * kk + 1) * 64], acc);
            }
            __builtin_amdgcn_s_setprio(0);
            int o = wave * 16 + m;
            float bias = db[o];
            float4 vv = {acc[0] + bias, acc[1] + bias, acc[2] + bias, acc[3] + bias};
            *(float4*)&out[((size_t)(b * 64 + o)) * HW + ho * 128 + wo0 + st * 16 + g * 4] = vv;
        }
        if (sp == 0) __syncthreads();
    }
}

extern "C" void kernel_launch(void* const* d_in, const int* in_sizes, int n_in,
                              void* d_out, int out_size, void* d_ws, size_t ws_size,
                              hipStream_t stream) {
    const float* x   = (const float*)d_in[0];
    const float* ow  = (const float*)d_in[1];
    const float* ob  = (const float*)d_in[2];
    const float* mw  = (const float*)d_in[3];
    const float* mb  = (const float*)d_in[4];
    const float* dw  = (const float*)d_in[5];
    const float* db  = (const float*)d_in[6];
    float* out = (float*)d_out;

    bf16* xt = (bf16*)d_ws;                         // 4,194,304 bf16 = 8 MB
    bf16* wfd_hi = xt + (size_t)BB * HW * CC;
    bf16* wfd_lo = wfd_hi + 36864;
    bf16* wfo_hi = wfd_lo + 36864;
    bf16* wfo_lo = wfo_hi + 18432;

    k_pre<<<1024 + 216, 256, 0, stream>>>(x, xt, dw, ow, mw, wfd_hi, wfd_lo, wfo_hi, wfo_lo);
    k_fused<<<(BB * HW) / 64, 256, 0, stream>>>(xt, wfo_hi, wfo_lo, wfd_hi, ob, mb, db, out);
}